// Round 7
// baseline (321.824 us; speedup 1.0000x reference)
//
#include <hip/hip_runtime.h>
#include <hip/hip_bf16.h>

typedef __attribute__((ext_vector_type(8))) short short8;
typedef __attribute__((ext_vector_type(4))) short short4v;
typedef __attribute__((ext_vector_type(16))) float f32x16;

constexpr int Bc = 4;
constexpr int Lc = 2048;
constexpr int Sc = 2048;
constexpr int Hc = 16;
constexpr int Ec = 64;
constexpr int Dc = 64;
constexpr int QBLK = 128;   // 4 waves x 32 q-rows
constexpr int KBLK = 64;

__device__ __forceinline__ unsigned short b16(float x) {
  __bf16 h = (__bf16)x;
  return __builtin_bit_cast(unsigned short, h);
}
__device__ __forceinline__ unsigned pk2(float lo, float hi) {
  return (unsigned)b16(lo) | ((unsigned)b16(hi) << 16);
}
__device__ __forceinline__ short8 cvt8(float4 a, float4 b) {
  short8 w;
  w[0] = (short)b16(a.x); w[1] = (short)b16(a.y);
  w[2] = (short)b16(a.z); w[3] = (short)b16(a.w);
  w[4] = (short)b16(b.x); w[5] = (short)b16(b.y);
  w[6] = (short)b16(b.z); w[7] = (short)b16(b.w);
  return w;
}
__device__ __forceinline__ short8 mk8(unsigned d0, unsigned d1, unsigned d2, unsigned d3) {
  union { unsigned u[4]; short8 s; } t;
  t.u[0] = d0; t.u[1] = d1; t.u[2] = d2; t.u[3] = d3;
  return t.s;
}

struct KV { float4 k[4]; float4 v[4]; };

__global__ __launch_bounds__(256, 3)
void fattn_kernel(const float* __restrict__ Qg, const float* __restrict__ Kg,
                  const float* __restrict__ Vg, float* __restrict__ Og) {
  // K tile (dbuf): rows s(64) x 64 bf16, 16B-chunk XOR swizzle by s&7
  __shared__ unsigned short Kl[2][KBLK * 64];
  // V tile (dbuf): subtiled [s/4][d/16][4][16] for ds_read_b64_tr_b16
  __shared__ unsigned short Vl[2][KBLK * 64];

  const int tid  = (int)threadIdx.x;
  const int wave = tid >> 6;
  const int lane = tid & 63;
  const int q32  = lane & 31;   // q column / d column / A-B row index
  const int hi   = lane >> 5;

  const int qtile = (int)gridDim.x - 1 - (int)blockIdx.x;  // heavy tiles first
  const int bh = (int)blockIdx.y;
  const int b  = bh >> 4;
  const int h  = bh & 15;
  const int qb = qtile * QBLK;
  const int q0w = qb + wave * 32;   // this wave's first q row

  // ---- Q fragments (B-operand): lane holds Q row q32, k-elems 16c+8hi+j ----
  const float QSCALE = 0.125f * 1.44269504088896341f;  // 1/sqrt(64) * log2(e)
  short8 qf[4];
  {
    const float* qp = Qg + (((size_t)(b * Lc + q0w + q32)) * Hc + h) * Ec;
#pragma unroll
    for (int c = 0; c < 4; ++c) {
      const float4* p4 = (const float4*)(qp + c * 16 + hi * 8);
      float4 x = p4[0], y = p4[1];
      x.x *= QSCALE; x.y *= QSCALE; x.z *= QSCALE; x.w *= QSCALE;
      y.x *= QSCALE; y.y *= QSCALE; y.z *= QSCALE; y.w *= QSCALE;
      qf[c] = cvt8(x, y);
    }
  }

  short8 ones;
#pragma unroll
  for (int j = 0; j < 8; ++j) ones[j] = (short)0x3F80;

  // staging geometry: thread owns row s, 16 consecutive elems at e0
  const int s  = tid >> 2;
  const int e0 = (tid & 3) << 4;

  auto loadKV = [&](int ch) {
    KV r;
    const size_t row = (((size_t)(b * Sc + ch * KBLK + s)) * Hc + h);
    const float4* kp4 = (const float4*)(Kg + row * Ec + e0);
    const float4* vp4 = (const float4*)(Vg + row * Dc + e0);
#pragma unroll
    for (int i = 0; i < 4; ++i) { r.k[i] = kp4[i]; r.v[i] = vp4[i]; }
    return r;
  };

  auto writeKV = [&](const KV& r, int buf) {
    short8 w0 = cvt8(r.k[0], r.k[1]);
    short8 w1 = cvt8(r.k[2], r.k[3]);
    const int c0 = e0 >> 3;
    *(short8*)&Kl[buf][s * 64 + (((c0    ) ^ (s & 7)) << 3)] = w0;
    *(short8*)&Kl[buf][s * 64 + (((c0 + 1) ^ (s & 7)) << 3)] = w1;
    short8 wv0 = cvt8(r.v[0], r.v[1]);
    short8 wv1 = cvt8(r.v[2], r.v[3]);
    const int vt = ((s >> 2) * 4 + (tid & 3)) * 64 + (s & 3) * 16;
    *(short8*)&Vl[buf][vt]     = wv0;
    *(short8*)&Vl[buf][vt + 8] = wv1;
  };

  f32x16 acco0 = (f32x16)(0.f), acco1 = (f32x16)(0.f), accl = (f32x16)(0.f);
  float m_run = -1e30f;   // running max, column layout (per q=q32, both halves)

  const int nch = 2 * qtile + 2;

  { KV r0 = loadKV(0); writeKV(r0, 0); }
  __syncthreads();

  int cur = 0;
  for (int ch = 0; ch < nch; ++ch) {
    const bool pref = (ch + 1 < nch);
    KV nxt;
    if (pref) nxt = loadKV(ch + 1);

    const int s0 = ch * 64;
    const bool act0  = (s0      <= q0w);
    const bool act1  = (s0 + 32 <= q0w);
    const bool diag0 = (s0      == q0w);
    const bool diag1 = (s0 + 32 == q0w);

    if (act0) {
      // ---- S^T = K Q^T  (swapped: rows=s, cols=q) ----
      auto qk = [&](int sb) {
        f32x16 acc = (f32x16)(0.f);
        const int sr = sb * 32 + q32;
        const int rb = sr * 64;
        const int sw = sr & 7;
#pragma unroll
        for (int c = 0; c < 4; ++c) {
          short8 kf = *(const short8*)&Kl[cur][rb + (((2 * c + hi) ^ sw) << 3)];
          acc = __builtin_amdgcn_mfma_f32_32x32x16_bf16(kf, qf[c], acc, 0, 0, 0);
        }
        return acc;
      };
      f32x16 S0 = qk(0);
      f32x16 S1;
      if (act1) S1 = qk(1);

      // diagonal mask: s_loc = (r&3)+8*(r>>2)+4*hi  >  q_loc = q32
      const int tq = q32 - 4 * hi;
      if (diag0) {
#pragma unroll
        for (int r = 0; r < 16; ++r)
          if (((r & 3) + 8 * (r >> 2)) > tq) S0[r] = -1e30f;
      }
      if (act1 && diag1) {
#pragma unroll
        for (int r = 0; r < 16; ++r)
          if (((r & 3) + 8 * (r >> 2)) > tq) S1[r] = -1e30f;
      }

      // ---- chunk max (in-lane + cross-half via permlane32_swap) ----
      float pmax = S0[0];
#pragma unroll
      for (int r = 1; r < 16; ++r) pmax = fmaxf(pmax, S0[r]);
      if (act1) {
#pragma unroll
        for (int r = 0; r < 16; ++r) pmax = fmaxf(pmax, S1[r]);
      }
      {
        unsigned px = __builtin_bit_cast(unsigned, pmax);
        auto sw = __builtin_amdgcn_permlane32_swap(px, px, false, false);
        pmax = fmaxf(__builtin_bit_cast(float, (unsigned)sw[0]),
                     __builtin_bit_cast(float, (unsigned)sw[1]));
      }

      // ---- defer-max: rescale only when max grew past THR (T13) ----
      if (!__all(pmax - m_run <= 8.0f)) {
        const float mnew  = fmaxf(m_run, pmax);
        const float alpha = exp2f(m_run - mnew);
        m_run = mnew;
        const int hib = hi << 4;
        const int av  = __builtin_bit_cast(int, alpha);
#pragma unroll
        for (int r = 0; r < 16; ++r) {
          const int addr = hib + 4 * ((r & 3) + 8 * (r >> 2));
          float ar = __builtin_bit_cast(float, __builtin_amdgcn_ds_bpermute(addr, av));
          acco0[r] *= ar; acco1[r] *= ar; accl[r] *= ar;
        }
      }

      // ---- P = exp2(S - m) (bounded by 2^8) ----
#pragma unroll
      for (int r = 0; r < 16; ++r) S0[r] = exp2f(S0[r] - m_run);
      if (act1) {
#pragma unroll
        for (int r = 0; r < 16; ++r) S1[r] = exp2f(S1[r] - m_run);
      }

      // ---- issue V transpose-reads early (latency hidden under pa build) ----
      const unsigned vbase = (unsigned)(size_t)(&Vl[cur][0]);
      const unsigned vcol  = ((unsigned)(q32 & 15) << 3);
      short4v vlo[2][4], vhi[2][4];
#pragma unroll
      for (int ks = 0; ks < 4; ++ks) {
        if (ks < 2 || act1) {
#pragma unroll
          for (int dt = 0; dt < 2; ++dt) {
            const unsigned a0 = vbase +
              ((((unsigned)(4 * ks + 2 * hi) * 4u) + 2u * dt + (unsigned)(q32 >> 4)) << 7) + vcol;
            asm volatile("ds_read_b64_tr_b16 %0, %1 offset:0"   : "=&v"(vlo[dt][ks]) : "v"(a0));
            asm volatile("ds_read_b64_tr_b16 %0, %1 offset:512" : "=&v"(vhi[dt][ks]) : "v"(a0));
          }
        }
      }

      // ---- build PV A-fragments: 16 cvt_pk + 8 permlane32_swap (T12) ----
      auto mkpa = [&](const f32x16& P, int a, int bidx) {
        unsigned A0 = pk2(P[4 * a + 0],    P[4 * a + 1]);
        unsigned A1 = pk2(P[4 * a + 2],    P[4 * a + 3]);
        unsigned B0 = pk2(P[4 * bidx + 0], P[4 * bidx + 1]);
        unsigned B1 = pk2(P[4 * bidx + 2], P[4 * bidx + 3]);
        auto r0 = __builtin_amdgcn_permlane32_swap(A0, B0, false, false);
        auto r1 = __builtin_amdgcn_permlane32_swap(A1, B1, false, false);
        return mk8((unsigned)r0[0], (unsigned)r1[0], (unsigned)r0[1], (unsigned)r1[1]);
      };
      short8 pa0 = mkpa(S0, 0, 1);
      short8 pa1 = mkpa(S0, 2, 3);
      short8 pa2, pa3;
      if (act1) { pa2 = mkpa(S1, 0, 1); pa3 = mkpa(S1, 2, 3); }

      asm volatile("s_waitcnt lgkmcnt(0)" ::: "memory");
      __builtin_amdgcn_sched_barrier(0);

      // ---- denominator via ones-MFMA (row layout matches acco) ----
      accl = __builtin_amdgcn_mfma_f32_32x32x16_bf16(pa0, ones, accl, 0, 0, 0);
      accl = __builtin_amdgcn_mfma_f32_32x32x16_bf16(pa1, ones, accl, 0, 0, 0);
      if (act1) {
        accl = __builtin_amdgcn_mfma_f32_32x32x16_bf16(pa2, ones, accl, 0, 0, 0);
        accl = __builtin_amdgcn_mfma_f32_32x32x16_bf16(pa3, ones, accl, 0, 0, 0);
      }

      // ---- O += P V ----
#pragma unroll
      for (int dt = 0; dt < 2; ++dt) {
        f32x16& ac = dt ? acco1 : acco0;
        short8 vf0 = __builtin_shufflevector(vlo[dt][0], vhi[dt][0], 0,1,2,3,4,5,6,7);
        short8 vf1 = __builtin_shufflevector(vlo[dt][1], vhi[dt][1], 0,1,2,3,4,5,6,7);
        ac = __builtin_amdgcn_mfma_f32_32x32x16_bf16(pa0, vf0, ac, 0, 0, 0);
        ac = __builtin_amdgcn_mfma_f32_32x32x16_bf16(pa1, vf1, ac, 0, 0, 0);
        if (act1) {
          short8 vf2 = __builtin_shufflevector(vlo[dt][2], vhi[dt][2], 0,1,2,3,4,5,6,7);
          short8 vf3 = __builtin_shufflevector(vlo[dt][3], vhi[dt][3], 0,1,2,3,4,5,6,7);
          ac = __builtin_amdgcn_mfma_f32_32x32x16_bf16(pa2, vf2, ac, 0, 0, 0);
          ac = __builtin_amdgcn_mfma_f32_32x32x16_bf16(pa3, vf3, ac, 0, 0, 0);
        }
      }
    }

    if (pref) writeKV(nxt, cur ^ 1);
    __syncthreads();
    cur ^= 1;
  }

  // ---- epilogue: O = acco / accl  (same row layout, no transport) ----
#pragma unroll
  for (int r = 0; r < 16; ++r) {
    const int q_loc = (r & 3) + 8 * (r >> 2) + 4 * hi;
    const int q = q0w + q_loc;
    const float inv = 1.0f / accl[r];
    float* op = Og + (((size_t)(b * Lc + q)) * Hc + h) * Dc + q32;
    op[0]  = acco0[r] * inv;
    op[32] = acco1[r] * inv;
  }
}

extern "C" void kernel_launch(void* const* d_in, const int* in_sizes, int n_in,
                              void* d_out, int out_size, void* d_ws, size_t ws_size,
                              hipStream_t stream) {
  const float* Q = (const float*)d_in[0];
  const float* K = (const float*)d_in[1];
  const float* V = (const float*)d_in[2];
  float* O = (float*)d_out;
  dim3 grid(Lc / QBLK, Bc * Hc);
  fattn_kernel<<<grid, 256, 0, stream>>>(Q, K, V, O);
}

// Round 8
// 111.856 us; speedup vs baseline: 2.8771x; 2.8771x over previous
//
#include <hip/hip_runtime.h>
#include <hip/hip_bf16.h>

typedef __attribute__((ext_vector_type(8))) short short8;
typedef __attribute__((ext_vector_type(4))) short short4v;
typedef __attribute__((ext_vector_type(16))) float f32x16;

constexpr int Bc = 4;
constexpr int Lc = 2048;
constexpr int Sc = 2048;
constexpr int Hc = 16;
constexpr int Ec = 64;
constexpr int Dc = 64;
constexpr int QBLK = 128;   // per tile: 4 waves x 32 q-rows; each block owns TWO tiles
constexpr int KBLK = 64;
constexpr int NQT  = Lc / QBLK;   // 16 q-tiles -> 8 complementary pairs

__device__ __forceinline__ unsigned short b16(float x) {
  __bf16 h = (__bf16)x;
  return __builtin_bit_cast(unsigned short, h);
}
__device__ __forceinline__ unsigned pk2(float lo, float hi) {
  return (unsigned)b16(lo) | ((unsigned)b16(hi) << 16);
}
__device__ __forceinline__ short8 cvt8(float4 a, float4 b) {
  short8 w;
  w[0] = (short)b16(a.x); w[1] = (short)b16(a.y);
  w[2] = (short)b16(a.z); w[3] = (short)b16(a.w);
  w[4] = (short)b16(b.x); w[5] = (short)b16(b.y);
  w[6] = (short)b16(b.z); w[7] = (short)b16(b.w);
  return w;
}
__device__ __forceinline__ short8 mk8(unsigned d0, unsigned d1, unsigned d2, unsigned d3) {
  union { unsigned u[4]; short8 s; } t;
  t.u[0] = d0; t.u[1] = d1; t.u[2] = d2; t.u[3] = d3;
  return t.s;
}

struct KV { float4 k[4]; float4 v[4]; };

__global__ __launch_bounds__(256, 2)
void fattn_kernel(const float* __restrict__ Qg, const float* __restrict__ Kg,
                  const float* __restrict__ Vg, float* __restrict__ Og) {
  // K tile (dbuf): rows s(64) x 64 bf16, 16B-chunk XOR swizzle by s&7
  __shared__ unsigned short Kl[2][KBLK * 64];
  // V tile (dbuf): subtiled [s/4][d/16][4][16] for ds_read_b64_tr_b16
  __shared__ unsigned short Vl[2][KBLK * 64];

  const int tid  = (int)threadIdx.x;
  const int wave = tid >> 6;
  const int lane = tid & 63;
  const int q32  = lane & 31;
  const int hi   = lane >> 5;

  const int pb = (int)blockIdx.x;          // pair index 0..7
  const int bh = (int)blockIdx.y;
  const int b  = bh >> 4;
  const int h  = bh & 15;

  const int qA   = pb;            // light tile
  const int qB   = NQT - 1 - pb;  // heavy tile
  const int q0A  = qA * QBLK + wave * 32;
  const int q0B  = qB * QBLK + wave * 32;
  const int nchA = 2 * pb + 2;
  const int nchB = 2 * qB + 2;    // = 32 - 2*pb  (>= nchA)

  const float QSCALE = 0.125f * 1.44269504088896341f;  // 1/sqrt(64) * log2(e)
  auto loadQ = [&](int q0, short8 (&qf)[4]) {
    const float* qp = Qg + (((size_t)(b * Lc + q0 + q32)) * Hc + h) * Ec;
#pragma unroll
    for (int c = 0; c < 4; ++c) {
      const float4* p4 = (const float4*)(qp + c * 16 + hi * 8);
      float4 x = p4[0], y = p4[1];
      x.x *= QSCALE; x.y *= QSCALE; x.z *= QSCALE; x.w *= QSCALE;
      y.x *= QSCALE; y.y *= QSCALE; y.z *= QSCALE; y.w *= QSCALE;
      qf[c] = cvt8(x, y);
    }
  };
  short8 qfA[4], qfB[4];
  loadQ(q0A, qfA);
  loadQ(q0B, qfB);

  short8 ones;
#pragma unroll
  for (int j = 0; j < 8; ++j) ones[j] = (short)0x3F80;

  // staging geometry: thread owns row s, 16 consecutive elems at e0
  const int s  = tid >> 2;
  const int e0 = (tid & 3) << 4;

  auto loadKV = [&](int ch) {
    KV r;
    const size_t row = (((size_t)(b * Sc + ch * KBLK + s)) * Hc + h);
    const float4* kp4 = (const float4*)(Kg + row * Ec + e0);
    const float4* vp4 = (const float4*)(Vg + row * Dc + e0);
#pragma unroll
    for (int i = 0; i < 4; ++i) { r.k[i] = kp4[i]; r.v[i] = vp4[i]; }
    return r;
  };

  auto writeKV = [&](const KV& r, int buf) {
    short8 w0 = cvt8(r.k[0], r.k[1]);
    short8 w1 = cvt8(r.k[2], r.k[3]);
    const int c0 = e0 >> 3;
    *(short8*)&Kl[buf][s * 64 + (((c0    ) ^ (s & 7)) << 3)] = w0;
    *(short8*)&Kl[buf][s * 64 + (((c0 + 1) ^ (s & 7)) << 3)] = w1;
    short8 wv0 = cvt8(r.v[0], r.v[1]);
    short8 wv1 = cvt8(r.v[2], r.v[3]);
    const int vt = ((s >> 2) * 4 + (tid & 3)) * 64 + (s & 3) * 16;
    *(short8*)&Vl[buf][vt]     = wv0;
    *(short8*)&Vl[buf][vt + 8] = wv1;
  };

  f32x16 accoA0 = (f32x16)(0.f), accoA1 = (f32x16)(0.f), acclA = (f32x16)(0.f);
  f32x16 accoB0 = (f32x16)(0.f), accoB1 = (f32x16)(0.f), acclB = (f32x16)(0.f);
  float mA = -1e30f, mB = -1e30f;

  // ---- one online-softmax + PV step for one tile on chunk ch ----
  auto doTile = [&](int ch, int cur, int q0w, const short8 (&qf)[4],
                    f32x16& acco0, f32x16& acco1, f32x16& accl, float& m_run) {
    const int s0 = ch * 64;
    const bool act0 = (s0 <= q0w);
    if (!act0) return;
    const bool act1  = (s0 + 32 <= q0w);
    const bool diag0 = (s0 == q0w);
    const bool diag1 = (s0 + 32 == q0w);

    // S^T = K Q^T (rows=s, cols=q)
    auto qk = [&](int sb) {
      f32x16 acc = (f32x16)(0.f);
      const int sr = sb * 32 + q32;
      const int rb = sr * 64;
      const int sw = sr & 7;
#pragma unroll
      for (int c = 0; c < 4; ++c) {
        short8 kf = *(const short8*)&Kl[cur][rb + (((2 * c + hi) ^ sw) << 3)];
        acc = __builtin_amdgcn_mfma_f32_32x32x16_bf16(kf, qf[c], acc, 0, 0, 0);
      }
      return acc;
    };
    f32x16 S0 = qk(0);
    f32x16 S1;
    if (act1) S1 = qk(1);

    const int tq = q32 - 4 * hi;
    if (diag0) {
#pragma unroll
      for (int r = 0; r < 16; ++r)
        if (((r & 3) + 8 * (r >> 2)) > tq) S0[r] = -1e30f;
    }
    if (act1 && diag1) {
#pragma unroll
      for (int r = 0; r < 16; ++r)
        if (((r & 3) + 8 * (r >> 2)) > tq) S1[r] = -1e30f;
    }

    // chunk max (in-lane + cross-half)
    float pmax = S0[0];
#pragma unroll
    for (int r = 1; r < 16; ++r) pmax = fmaxf(pmax, S0[r]);
    if (act1) {
#pragma unroll
      for (int r = 0; r < 16; ++r) pmax = fmaxf(pmax, S1[r]);
    }
    {
      unsigned px = __builtin_bit_cast(unsigned, pmax);
      auto sw = __builtin_amdgcn_permlane32_swap(px, px, false, false);
      pmax = fmaxf(__builtin_bit_cast(float, (unsigned)sw[0]),
                   __builtin_bit_cast(float, (unsigned)sw[1]));
    }

    // defer-max rescale (T13)
    if (!__all(pmax - m_run <= 8.0f)) {
      const float mnew  = fmaxf(m_run, pmax);
      const float alpha = exp2f(m_run - mnew);
      m_run = mnew;
      const int hib = hi << 4;
      const int av  = __builtin_bit_cast(int, alpha);
#pragma unroll
      for (int r = 0; r < 16; ++r) {
        const int addr = hib + 4 * ((r & 3) + 8 * (r >> 2));
        float ar = __builtin_bit_cast(float, __builtin_amdgcn_ds_bpermute(addr, av));
        acco0[r] *= ar; acco1[r] *= ar; accl[r] *= ar;
      }
    }

    // P = exp2(S - m)
#pragma unroll
    for (int r = 0; r < 16; ++r) S0[r] = exp2f(S0[r] - m_run);
    if (act1) {
#pragma unroll
      for (int r = 0; r < 16; ++r) S1[r] = exp2f(S1[r] - m_run);
    }

    // PV A-fragments first (S dies -> lower reg peak)
    auto mkpa = [&](const f32x16& P, int a, int bidx) {
      unsigned A0 = pk2(P[4 * a + 0],    P[4 * a + 1]);
      unsigned A1 = pk2(P[4 * a + 2],    P[4 * a + 3]);
      unsigned B0 = pk2(P[4 * bidx + 0], P[4 * bidx + 1]);
      unsigned B1 = pk2(P[4 * bidx + 2], P[4 * bidx + 3]);
      auto r0 = __builtin_amdgcn_permlane32_swap(A0, B0, false, false);
      auto r1 = __builtin_amdgcn_permlane32_swap(A1, B1, false, false);
      return mk8((unsigned)r0[0], (unsigned)r1[0], (unsigned)r0[1], (unsigned)r1[1]);
    };
    short8 pa0 = mkpa(S0, 0, 1);
    short8 pa1 = mkpa(S0, 2, 3);
    short8 pa2, pa3;
    if (act1) { pa2 = mkpa(S1, 0, 1); pa3 = mkpa(S1, 2, 3); }

    // issue V transpose-reads
    const unsigned vbase = (unsigned)(size_t)(&Vl[cur][0]);
    const unsigned vcol  = ((unsigned)(q32 & 15) << 3);
    short4v vlo[2][4], vhi[2][4];
#pragma unroll
    for (int ks = 0; ks < 4; ++ks) {
      if (ks < 2 || act1) {
#pragma unroll
        for (int dt = 0; dt < 2; ++dt) {
          const unsigned a0 = vbase +
            ((((unsigned)(4 * ks + 2 * hi) * 4u) + 2u * dt + (unsigned)(q32 >> 4)) << 7) + vcol;
          asm volatile("ds_read_b64_tr_b16 %0, %1 offset:0"   : "=&v"(vlo[dt][ks]) : "v"(a0));
          asm volatile("ds_read_b64_tr_b16 %0, %1 offset:512" : "=&v"(vhi[dt][ks]) : "v"(a0));
        }
      }
    }

    // denominator MFMAs (independent of tr-reads -> hide their latency)
    accl = __builtin_amdgcn_mfma_f32_32x32x16_bf16(pa0, ones, accl, 0, 0, 0);
    accl = __builtin_amdgcn_mfma_f32_32x32x16_bf16(pa1, ones, accl, 0, 0, 0);
    if (act1) {
      accl = __builtin_amdgcn_mfma_f32_32x32x16_bf16(pa2, ones, accl, 0, 0, 0);
      accl = __builtin_amdgcn_mfma_f32_32x32x16_bf16(pa3, ones, accl, 0, 0, 0);
    }

    asm volatile("s_waitcnt lgkmcnt(0)" ::: "memory");
    __builtin_amdgcn_sched_barrier(0);

    // O += P V
#pragma unroll
    for (int dt = 0; dt < 2; ++dt) {
      f32x16& ac = dt ? acco1 : acco0;
      short8 vf0 = __builtin_shufflevector(vlo[dt][0], vhi[dt][0], 0,1,2,3,4,5,6,7);
      short8 vf1 = __builtin_shufflevector(vlo[dt][1], vhi[dt][1], 0,1,2,3,4,5,6,7);
      ac = __builtin_amdgcn_mfma_f32_32x32x16_bf16(pa0, vf0, ac, 0, 0, 0);
      ac = __builtin_amdgcn_mfma_f32_32x32x16_bf16(pa1, vf1, ac, 0, 0, 0);
      if (act1) {
        short8 vf2 = __builtin_shufflevector(vlo[dt][2], vhi[dt][2], 0,1,2,3,4,5,6,7);
        short8 vf3 = __builtin_shufflevector(vlo[dt][3], vhi[dt][3], 0,1,2,3,4,5,6,7);
        ac = __builtin_amdgcn_mfma_f32_32x32x16_bf16(pa2, vf2, ac, 0, 0, 0);
        ac = __builtin_amdgcn_mfma_f32_32x32x16_bf16(pa3, vf3, ac, 0, 0, 0);
      }
    }
  };

  // prologue: stage chunk 0 into buf 0
  { KV r0 = loadKV(0); writeKV(r0, 0); }
  __syncthreads();

  int cur = 0;
  for (int ch = 0; ch < nchB; ++ch) {
    const bool pref = (ch + 1 < nchB);
    KV nxt;
    if (pref) nxt = loadKV(ch + 1);

    // heavy tile first (always active), then light tile while it lasts
    doTile(ch, cur, q0B, qfB, accoB0, accoB1, acclB, mB);
    if (ch < nchA) doTile(ch, cur, q0A, qfA, accoA0, accoA1, acclA, mA);

    if (pref) writeKV(nxt, cur ^ 1);
    __syncthreads();
    cur ^= 1;
  }

  // ---- epilogue: O = acco / accl for both tiles ----
  auto epi = [&](int q0w, const f32x16& acco0, const f32x16& acco1, const f32x16& accl) {
#pragma unroll
    for (int r = 0; r < 16; ++r) {
      const int q_loc = (r & 3) + 8 * (r >> 2) + 4 * hi;
      const int q = q0w + q_loc;
      const float inv = 1.0f / accl[r];
      float* op = Og + (((size_t)(b * Lc + q)) * Hc + h) * Dc + q32;
      op[0]  = acco0[r] * inv;
      op[32] = acco1[r] * inv;
    }
  };
  epi(q0A, accoA0, accoA1, acclA);
  epi(q0B, accoB0, accoB1, acclB);
}

extern "C" void kernel_launch(void* const* d_in, const int* in_sizes, int n_in,
                              void* d_out, int out_size, void* d_ws, size_t ws_size,
                              hipStream_t stream) {
  const float* Q = (const float*)d_in[0];
  const float* K = (const float*)d_in[1];
  const float* V = (const float*)d_in[2];
  float* O = (float*)d_out;
  dim3 grid(NQT / 2, Bc * Hc);   // 8 complementary pairs x 64 (b,h)
  fattn_kernel<<<grid, 256, 0, stream>>>(Q, K, V, O);
}